// Round 1
// baseline (8695.336 us; speedup 1.0000x reference)
//
#include <hip/hip_runtime.h>
#include <math.h>

#define B 8
#define LATD 512
#define PT 45376
#define FIN 192
#define FH 64
#define OW1 0
#define OB1 12288
#define OW2 12352
#define OB2 20544
#define OWS 20672
#define OBS 45248

__device__ __forceinline__ float gk_at(int ky, int kx){
  const float a = 0.60653065971263342f;
  const float inv = 1.0f / ((1.0f + 2.0f*a) * (1.0f + 2.0f*a));
  float wy = (ky==1) ? 1.0f : a;
  float wx = (kx==1) ? 1.0f : a;
  return wy * wx * inv;
}

// p[b][j] = sum_k lat[b][k] * hyper_w[k][j] + hyper_b[j]
__global__ void k_hyper(const float* __restrict__ lat, const float* __restrict__ hw,
                        const float* __restrict__ hb, float* __restrict__ p){
  __shared__ float slat[B*LATD];
  for (int idx = threadIdx.x; idx < B*LATD; idx += 256) slat[idx] = lat[idx];
  __syncthreads();
  int j = blockIdx.x*256 + threadIdx.x;
  if (j >= PT) return;
  float acc[B];
#pragma unroll
  for (int b=0;b<B;++b) acc[b]=0.f;
  for (int k=0;k<LATD;++k){
    float w = hw[(size_t)k*PT + j];
#pragma unroll
    for (int b=0;b<B;++b) acc[b] = fmaf(slat[b*LATD+k], w, acc[b]);
  }
  float bias = hb[j];
#pragma unroll
  for (int b=0;b<B;++b) p[(size_t)b*PT + j] = acc[b] + bias;
}

// out = gauss_blur(ca_noise) at 16x16  (inst_norm(broadcast(seed)) == 0 exactly)
__global__ void k_init(const float* __restrict__ noise, float* __restrict__ out){
  int bc = blockIdx.x;
  int t = threadIdx.x;
  int y = t >> 4, x = t & 15;
  const float* src = noise + (size_t)bc*256;
  float acc = 0.f;
#pragma unroll
  for (int ky=0;ky<3;++ky){
    int yy = y+ky-1; if (yy < 0 || yy > 15) continue;
#pragma unroll
    for (int kx=0;kx<3;++kx){
      int xx = x+kx-1; if (xx < 0 || xx > 15) continue;
      acc = fmaf(gk_at(ky,kx), src[yy*16+xx], acc);
    }
  }
  out[(size_t)bc*256 + t] = acc;
}

// sobel channels + per-(b,c) mean/rstd for all 192 z-channels
__global__ void k_sobelstats(const float* __restrict__ out, float* __restrict__ sob,
                             float* __restrict__ stats, int H, int lgH, int HW){
  int bc = blockIdx.x; int b = bc/192, c = bc - b*192;
  int t = threadIdx.x;
  float s = 0.f, ss = 0.f;
  if (c < 64){
    const float* src = out + ((size_t)b*64 + c)*(size_t)HW;
    for (int px = t; px < HW; px += 256){ float v = src[px]; s += v; ss = fmaf(v,v,ss); }
  } else {
    int cc = (c-64) & 63;
    int isY = (c >= 128);
    const float* src = out + ((size_t)b*64 + cc)*(size_t)HW;
    float* dst = sob + ((size_t)b*128 + (c-64))*(size_t)HW;
    for (int px = t; px < HW; px += 256){
      int y = px >> lgH, x = px & (H-1);
      float acc = 0.f;
#pragma unroll
      for (int ky=0;ky<3;++ky){
        int yy = y+ky-1; if (yy < 0 || yy >= H) continue;
        float vy = (ky==1)?2.f:1.f, dy = (float)(ky-1);
#pragma unroll
        for (int kx=0;kx<3;++kx){
          int xx = x+kx-1; if (xx < 0 || xx >= H) continue;
          float vx = (kx==1)?2.f:1.f, dx = (float)(kx-1);
          float w = isY ? dy*vx : vy*dx;
          if (w == 0.f) continue;
          acc = fmaf(w*0.125f, src[yy*H+xx], acc);
        }
      }
      dst[px] = acc; s += acc; ss = fmaf(acc,acc,ss);
    }
  }
  __shared__ float r1[256], r2[256];
  r1[t] = s; r2[t] = ss; __syncthreads();
  for (int off=128; off>0; off>>=1){
    if (t < off){ r1[t] += r1[t+off]; r2[t] += r2[t+off]; }
    __syncthreads();
  }
  if (t == 0){
    float inv = 1.0f/(float)HW;
    float m = r1[0]*inv;
    float var = fmaxf(r2[0]*inv - m*m, 0.f);
    stats[bc*2]   = m;
    stats[bc*2+1] = 1.0f/sqrtf(var + 1e-5f);
  }
}

__device__ __forceinline__ float4 load_xn(const float* out, const float* __restrict__ sob,
                                          const float* __restrict__ stats,
                                          int b, int i, int px4, int HW){
  const float* src = (i < 64) ? (out + ((size_t)(b*64 + i))*(size_t)HW)
                              : (sob + ((size_t)(b*128 + (i-64)))*(size_t)HW);
  float4 v = *(const float4*)(src + px4);
  float m = stats[(b*192+i)*2], r = stats[(b*192+i)*2+1];
  v.x = (v.x-m)*r; v.y = (v.y-m)*r; v.z = (v.z-m)*r; v.w = (v.w-m)*r;
  return v;
}

// h = relu(W1 @ xn + b1)   — 64 outputs, K = 192
__global__ void __launch_bounds__(512) k_gemm1(const float* __restrict__ out, const float* __restrict__ sob,
                       const float* __restrict__ stats, const float* __restrict__ p,
                       float* __restrict__ hbuf, int HW){
  __shared__ float wlds[32][68];
  int b = blockIdx.y;
  int tx = threadIdx.x, ty = threadIdx.y;
  int tid = ty*32 + tx;
  int px4 = (blockIdx.x*32 + tx)*4;
  int o0 = ty*4;
  const float* pw = p + (size_t)b*PT;
  float acc[4][4];
#pragma unroll
  for (int k=0;k<4;++k){
#pragma unroll
    for (int j=0;j<4;++j) acc[k][j]=0.f;
  }
  for (int ci=0; ci<6; ++ci){
    for (int idx=tid; idx<32*64; idx+=512){
      int o = idx >> 5, ii = idx & 31;
      wlds[ii][o] = pw[OW1 + o*FIN + (ci*32+ii)];
    }
    __syncthreads();
#pragma unroll
    for (int ii=0; ii<32; ++ii){
      int i = ci*32 + ii;
      float4 xv = load_xn(out, sob, stats, b, i, px4, HW);
      float xvv[4] = {xv.x, xv.y, xv.z, xv.w};
      float w[4];
#pragma unroll
      for (int k=0;k<4;++k) w[k] = wlds[ii][o0+k];
#pragma unroll
      for (int k=0;k<4;++k)
#pragma unroll
        for (int j=0;j<4;++j) acc[k][j] = fmaf(w[k], xvv[j], acc[k][j]);
    }
    __syncthreads();
  }
#pragma unroll
  for (int k=0;k<4;++k){
    float bias = pw[OB1 + o0 + k];
    float4 hv;
    hv.x = fmaxf(acc[k][0]+bias, 0.f);
    hv.y = fmaxf(acc[k][1]+bias, 0.f);
    hv.z = fmaxf(acc[k][2]+bias, 0.f);
    hv.w = fmaxf(acc[k][3]+bias, 0.f);
    *(float4*)(hbuf + ((size_t)(b*64 + o0+k))*(size_t)HW + px4) = hv;
  }
}

// z2 = [Ws|W2] @ [xn;h] + (bs+b2); gate; out += lf * z * sigmoid(g)   — 128 outputs, K = 256
__global__ void __launch_bounds__(512) k_gemm2(float* out, const float* __restrict__ sob,
                       const float* __restrict__ stats, const float* __restrict__ p,
                       const float* __restrict__ hbuf, const float* __restrict__ lfp,
                       int HW){
  __shared__ float wlds[32][132];
  int b = blockIdx.y;
  int tx = threadIdx.x, ty = threadIdx.y;
  int tid = ty*32 + tx;
  int px4 = (blockIdx.x*32 + tx)*4;
  int zo = ty*4;
  const float* pw = p + (size_t)b*PT;
  float az[4][4], ag[4][4];
#pragma unroll
  for (int k=0;k<4;++k){
#pragma unroll
    for (int j=0;j<4;++j){ az[k][j]=0.f; ag[k][j]=0.f; }
  }
  for (int ci=0; ci<8; ++ci){
    for (int idx=tid; idx<32*128; idx+=512){
      int o = idx >> 5, ii = idx & 31;
      int i = ci*32 + ii;
      wlds[ii][o] = (i < 192) ? pw[OWS + o*FIN + i] : pw[OW2 + o*FH + (i-192)];
    }
    __syncthreads();
#pragma unroll
    for (int ii=0; ii<32; ++ii){
      int i = ci*32 + ii;
      float4 xv;
      if (i < 192) xv = load_xn(out, sob, stats, b, i, px4, HW);
      else         xv = *(const float4*)(hbuf + ((size_t)(b*64 + (i-192)))*(size_t)HW + px4);
      float xvv[4] = {xv.x, xv.y, xv.z, xv.w};
      float wz[4], wg[4];
#pragma unroll
      for (int k=0;k<4;++k){ wz[k] = wlds[ii][zo+k]; wg[k] = wlds[ii][zo+64+k]; }
#pragma unroll
      for (int k=0;k<4;++k)
#pragma unroll
        for (int j=0;j<4;++j){
          az[k][j] = fmaf(wz[k], xvv[j], az[k][j]);
          ag[k][j] = fmaf(wg[k], xvv[j], ag[k][j]);
        }
    }
    __syncthreads();  // last barrier also protects the in-place out update below
  }
  float lf = fminf(fmaxf(lfp[0], 0.001f), 1000.f);
#pragma unroll
  for (int k=0;k<4;++k){
    int o = zo + k;
    float bz = pw[OB2 + o]      + pw[OBS + o];
    float bg = pw[OB2 + o + 64] + pw[OBS + o + 64];
    float* op = out + ((size_t)(b*64 + o))*(size_t)HW + px4;
    float4 ov = *(const float4*)op;
    float zv[4] = {az[k][0]+bz, az[k][1]+bz, az[k][2]+bz, az[k][3]+bz};
    float gv[4] = {ag[k][0]+bg, ag[k][1]+bg, ag[k][2]+bg, ag[k][3]+bg};
    float rv[4];
#pragma unroll
    for (int j=0;j<4;++j) rv[j] = lf * zv[j] / (1.f + expf(-gv[j]));
    ov.x += rv[0]; ov.y += rv[1]; ov.z += rv[2]; ov.w += rv[3];
    *(float4*)op = ov;
  }
}

// dst(2H x 2H) = gauss_blur( bilinear_up2(src) ), zero-padded blur, clamped bilinear
__global__ void k_upsample(const float* __restrict__ src, float* __restrict__ dst, int H, int lgH){
  int Hn = 2*H;
  int HWn = Hn*Hn;
  int bc = blockIdx.y;
  int opx = blockIdx.x*256 + threadIdx.x;
  const float* s = src + (size_t)bc*(size_t)(H*H);
  int oy = opx >> (lgH+1), ox = opx & (Hn-1);
  float acc = 0.f;
#pragma unroll
  for (int ky=0;ky<3;++ky){
    int yy = oy+ky-1; if (yy < 0 || yy >= Hn) continue;
    int iy = yy >> 1, ry = yy & 1;
    int y0 = ry ? iy : iy-1;
    int y1 = ry ? iy+1 : iy;
    float wy0 = ry ? 0.75f : 0.25f;
    float wy1 = 1.f - wy0;
    y0 = y0 < 0 ? 0 : y0;
    y1 = y1 > H-1 ? H-1 : y1;
#pragma unroll
    for (int kx=0;kx<3;++kx){
      int xx = ox+kx-1; if (xx < 0 || xx >= Hn) continue;
      int ix = xx >> 1, rx = xx & 1;
      int x0 = rx ? ix : ix-1;
      int x1 = rx ? ix+1 : ix;
      float wx0 = rx ? 0.75f : 0.25f;
      float wx1 = 1.f - wx0;
      x0 = x0 < 0 ? 0 : x0;
      x1 = x1 > H-1 ? H-1 : x1;
      float u = wy0*(wx0*s[y0*H+x0] + wx1*s[y0*H+x1])
              + wy1*(wx0*s[y1*H+x0] + wx1*s[y1*H+x1]);
      acc = fmaf(gk_at(ky,kx), u, acc);
    }
  }
  dst[(size_t)bc*(size_t)HWn + opx] = acc;
}

// y = W(64x64) @ in + bias, optional relu, optional += addb
__global__ void __launch_bounds__(512) k_lin64(const float* __restrict__ in, const float* __restrict__ w,
                       const float* __restrict__ bias, const float* __restrict__ addb,
                       float* __restrict__ outp, int HW, int relu){
  __shared__ float wlds[64][68];
  int tid = threadIdx.y*32 + threadIdx.x;
  for (int idx=tid; idx<4096; idx+=512){
    int o = idx >> 6, i = idx & 63;
    wlds[i][o] = w[o*64+i];
  }
  __syncthreads();
  int b = blockIdx.y;
  int px4 = (blockIdx.x*32 + threadIdx.x)*4;
  int o0 = threadIdx.y*4;
  float acc[4][4];
#pragma unroll
  for (int k=0;k<4;++k){
#pragma unroll
    for (int j=0;j<4;++j) acc[k][j]=0.f;
  }
#pragma unroll 8
  for (int i=0;i<64;++i){
    float4 xv = *(const float4*)(in + ((size_t)(b*64+i))*(size_t)HW + px4);
    float xvv[4] = {xv.x, xv.y, xv.z, xv.w};
    float wv[4];
#pragma unroll
    for (int k=0;k<4;++k) wv[k] = wlds[i][o0+k];
#pragma unroll
    for (int k=0;k<4;++k)
#pragma unroll
      for (int j=0;j<4;++j) acc[k][j] = fmaf(wv[k], xvv[j], acc[k][j]);
  }
#pragma unroll
  for (int k=0;k<4;++k){
    int o = o0+k;
    float bs = bias[o];
    float4 r;
    r.x = acc[k][0]+bs; r.y = acc[k][1]+bs; r.z = acc[k][2]+bs; r.w = acc[k][3]+bs;
    if (relu){
      r.x = fmaxf(r.x,0.f); r.y = fmaxf(r.y,0.f); r.z = fmaxf(r.z,0.f); r.w = fmaxf(r.w,0.f);
    }
    if (addb){
      float4 a = *(const float4*)(addb + ((size_t)(b*64+o))*(size_t)HW + px4);
      r.x += a.x; r.y += a.y; r.z += a.z; r.w += a.w;
    }
    *(float4*)(outp + ((size_t)(b*64+o))*(size_t)HW + px4) = r;
  }
}

// y = outc_w(3x64) @ t + outc_b ; write clip(y) then raw y
__global__ void k_out3(const float* __restrict__ t, const float* __restrict__ ow,
                       const float* __restrict__ ob, float* __restrict__ dout, int HW){
  int b = blockIdx.y;
  int px4 = (blockIdx.x*256 + threadIdx.x)*4;
  float a0[4] = {0,0,0,0}, a1[4] = {0,0,0,0}, a2[4] = {0,0,0,0};
  for (int i=0;i<64;++i){
    float4 tv = *(const float4*)(t + ((size_t)(b*64+i))*(size_t)HW + px4);
    float tvv[4] = {tv.x, tv.y, tv.z, tv.w};
    float w0 = ow[i], w1 = ow[64+i], w2 = ow[128+i];
#pragma unroll
    for (int j=0;j<4;++j){
      a0[j] = fmaf(w0, tvv[j], a0[j]);
      a1[j] = fmaf(w1, tvv[j], a1[j]);
      a2[j] = fmaf(w2, tvv[j], a2[j]);
    }
  }
  size_t rawoff = (size_t)B*3*(size_t)HW;
  float bb[3] = {ob[0], ob[1], ob[2]};
  float* accs[3] = {a0, a1, a2};
#pragma unroll
  for (int c=0;c<3;++c){
    float4 raw, clp;
    float* a = accs[c];
    float y0 = a[0]+bb[c], y1 = a[1]+bb[c], y2 = a[2]+bb[c], y3 = a[3]+bb[c];
    raw.x = y0; raw.y = y1; raw.z = y2; raw.w = y3;
    clp.x = fminf(fmaxf(y0,-1.f),1.f);
    clp.y = fminf(fmaxf(y1,-1.f),1.f);
    clp.z = fminf(fmaxf(y2,-1.f),1.f);
    clp.w = fminf(fmaxf(y3,-1.f),1.f);
    size_t base = ((size_t)(b*3+c))*(size_t)HW + px4;
    *(float4*)(dout + base) = clp;
    *(float4*)(dout + rawoff + base) = raw;
  }
}

extern "C" void kernel_launch(void* const* d_in, const int* in_sizes, int n_in,
                              void* d_out, int out_size, void* d_ws, size_t ws_size,
                              hipStream_t stream) {
  const float* lat = (const float*)d_in[0];
  const float* ca  = (const float*)d_in[1];
  const float* lfp = (const float*)d_in[3];
  const float* hw  = (const float*)d_in[4];
  const float* hb  = (const float*)d_in[5];
  const float* r1w = (const float*)d_in[6];
  const float* r1b = (const float*)d_in[7];
  const float* r2w = (const float*)d_in[8];
  const float* r2b = (const float*)d_in[9];
  const float* ocw = (const float*)d_in[10];
  const float* ocb = (const float*)d_in[11];
  float* dout = (float*)d_out;

  float* ws   = (float*)d_ws;
  float* p    = ws;                                     // B*PT
  float* outA = p    + (size_t)B*PT;                    // B*64*16384
  float* outB = outA + (size_t)B*64*16384;              // B*64*16384
  float* sob  = outB + (size_t)B*64*16384;              // B*128*16384
  float* hbuf = sob  + (size_t)B*128*16384;             // B*64*16384
  float* stats= hbuf + (size_t)B*64*16384;              // B*192*2
  float* tbuf = sob;                                    // reuse after loop

  k_hyper<<<dim3((PT+255)/256), dim3(256), 0, stream>>>(lat, hw, hb, p);
  k_init<<<dim3(B*64), dim3(256), 0, stream>>>(ca, outA);

  float* cur = outA;
  float* oth = outB;
  int H = 16, lgH = 4;
  for (int c = 0; c < 16; ++c){
    int HW = H*H;
    k_sobelstats<<<dim3(B*192), dim3(256), 0, stream>>>(cur, sob, stats, H, lgH, HW);
    dim3 g(HW/128, B), blk(32,16);
    k_gemm1<<<g, blk, 0, stream>>>(cur, sob, stats, p, hbuf, HW);
    k_gemm2<<<g, blk, 0, stream>>>(cur, sob, stats, p, hbuf, lfp, HW);
    if (c < 15 && (c & 3) == 3){
      k_upsample<<<dim3((HW*4)/256, B*64), dim3(256), 0, stream>>>(cur, oth, H, lgH);
      float* tmp = cur; cur = oth; oth = tmp;
      H *= 2; lgH += 1;
    }
  }
  int HW = H*H;  // 16384
  dim3 g(HW/128, B), blk(32,16);
  k_lin64<<<g, blk, 0, stream>>>(cur, r1w, r1b, nullptr, hbuf, HW, 1);
  k_lin64<<<g, blk, 0, stream>>>(hbuf, r2w, r2b, cur, tbuf, HW, 0);
  k_out3<<<dim3(HW/1024, B), dim3(256), 0, stream>>>(tbuf, ocw, ocb, dout, HW);
}

// Round 2
// 2537.321 us; speedup vs baseline: 3.4270x; 3.4270x over previous
//
#include <hip/hip_runtime.h>
#include <math.h>

#define B 8
#define LATD 512
#define PT 45376
#define FIN 192
#define FH 64
#define OW1 0
#define OB1 12288
#define OW2 12352
#define OB2 20544
#define OWS 20672
#define OBS 45248
#define TPX 128   // pixel tile per block
#define KC 16     // K chunk

__device__ __forceinline__ float gk_at(int ky, int kx){
  const float a = 0.60653065971263342f;
  const float inv = 1.0f / ((1.0f + 2.0f*a) * (1.0f + 2.0f*a));
  float wy = (ky==1) ? 1.0f : a;
  float wx = (kx==1) ? 1.0f : a;
  return wy * wx * inv;
}

// p[b][j] = sum_k lat[b][k] * hyper_w[k][j] + hyper_b[j]
__global__ void k_hyper(const float* __restrict__ lat, const float* __restrict__ hw,
                        const float* __restrict__ hb, float* __restrict__ p){
  __shared__ float slat[B*LATD];
  for (int idx = threadIdx.x; idx < B*LATD; idx += 256) slat[idx] = lat[idx];
  __syncthreads();
  int j = blockIdx.x*256 + threadIdx.x;
  if (j >= PT) return;
  float acc[B];
#pragma unroll
  for (int b=0;b<B;++b) acc[b]=0.f;
  for (int k=0;k<LATD;++k){
    float w = hw[(size_t)k*PT + j];
#pragma unroll
    for (int b=0;b<B;++b) acc[b] = fmaf(slat[b*LATD+k], w, acc[b]);
  }
  float bias = hb[j];
#pragma unroll
  for (int b=0;b<B;++b) p[(size_t)b*PT + j] = acc[b] + bias;
}

// out = gauss_blur(ca_noise) at 16x16  (inst_norm(broadcast(seed)) == 0 exactly)
__global__ void k_init(const float* __restrict__ noise, float* __restrict__ out){
  int bc = blockIdx.x;
  int t = threadIdx.x;
  int y = t >> 4, x = t & 15;
  const float* src = noise + (size_t)bc*256;
  float acc = 0.f;
#pragma unroll
  for (int ky=0;ky<3;++ky){
    int yy = y+ky-1; if (yy < 0 || yy > 15) continue;
#pragma unroll
    for (int kx=0;kx<3;++kx){
      int xx = x+kx-1; if (xx < 0 || xx > 15) continue;
      acc = fmaf(gk_at(ky,kx), src[yy*16+xx], acc);
    }
  }
  out[(size_t)bc*256 + t] = acc;
}

// sobel channels + per-(b,c) mean/rstd for all 192 z-channels
__global__ void k_sobelstats(const float* __restrict__ out, float* __restrict__ sob,
                             float* __restrict__ stats, int H, int lgH, int HW){
  int bc = blockIdx.x; int b = bc/192, c = bc - b*192;
  int t = threadIdx.x;
  float s = 0.f, ss = 0.f;
  if (c < 64){
    const float* src = out + ((size_t)b*64 + c)*(size_t)HW;
    for (int px = t; px < HW; px += 256){ float v = src[px]; s += v; ss = fmaf(v,v,ss); }
  } else {
    int cc = (c-64) & 63;
    int isY = (c >= 128);
    const float* src = out + ((size_t)b*64 + cc)*(size_t)HW;
    float* dst = sob + ((size_t)b*128 + (c-64))*(size_t)HW;
    for (int px = t; px < HW; px += 256){
      int y = px >> lgH, x = px & (H-1);
      float acc = 0.f;
#pragma unroll
      for (int ky=0;ky<3;++ky){
        int yy = y+ky-1; if (yy < 0 || yy >= H) continue;
        float vy = (ky==1)?2.f:1.f, dy = (float)(ky-1);
#pragma unroll
        for (int kx=0;kx<3;++kx){
          int xx = x+kx-1; if (xx < 0 || xx >= H) continue;
          float vx = (kx==1)?2.f:1.f, dx = (float)(kx-1);
          float w = isY ? dy*vx : vy*dx;
          if (w == 0.f) continue;
          acc = fmaf(w*0.125f, src[yy*H+xx], acc);
        }
      }
      dst[px] = acc; s += acc; ss = fmaf(acc,acc,ss);
    }
  }
  __shared__ float r1[256], r2[256];
  r1[t] = s; r2[t] = ss; __syncthreads();
  for (int off=128; off>0; off>>=1){
    if (t < off){ r1[t] += r1[t+off]; r2[t] += r2[t+off]; }
    __syncthreads();
  }
  if (t == 0){
    float inv = 1.0f/(float)HW;
    float m = r1[0]*inv;
    float var = fmaxf(r2[0]*inv - m*m, 0.f);
    stats[bc*2]   = m;
    stats[bc*2+1] = 1.0f/sqrtf(var + 1e-5f);
  }
}

// load one float4 of the concatenated K input [xn(192, normalized) ; h(64)]
__device__ __forceinline__ float4 ldx(const float* __restrict__ out, const float* __restrict__ sob,
                                      const float* __restrict__ stats, const float* __restrict__ hbuf,
                                      int b, int i, int off, int HW){
  float4 v;
  if (i < 192){
    const float* src = (i < 64) ? out + ((size_t)(b*64+i))*(size_t)HW
                                : sob + ((size_t)(b*128+(i-64)))*(size_t)HW;
    v = *(const float4*)(src + off);
    float m = stats[(b*192+i)*2], r = stats[(b*192+i)*2+1];
    v.x=(v.x-m)*r; v.y=(v.y-m)*r; v.z=(v.z-m)*r; v.w=(v.w-m)*r;
  } else {
    v = *(const float4*)(hbuf + ((size_t)(b*64+(i-192)))*(size_t)HW + off);
  }
  return v;
}

// h = relu(W1 @ xn + b1) : 64 outputs, K=192. block (16,8)=128 thr, tile 64out x 128px
__global__ void __launch_bounds__(128) k_gemm1n(const float* __restrict__ out, const float* __restrict__ sob,
                       const float* __restrict__ stats, const float* __restrict__ p,
                       float* __restrict__ hbuf, int HW){
  __shared__ float Xs[KC][132];
  __shared__ float Ws[KC][68];
  int b = blockIdx.y;
  int tx = threadIdx.x, ty = threadIdx.y;      // tx:0..15, ty:0..7
  int tid = ty*16 + tx;
  int px0 = blockIdx.x*TPX;
  const float* pw = p + (size_t)b*PT;
  float acc[8][8];
#pragma unroll
  for (int k=0;k<8;++k)
#pragma unroll
    for (int j=0;j<8;++j) acc[k][j]=0.f;

  for (int ci=0; ci<12; ++ci){
    // stage X chunk [16ch][128px]: 512 float4, 4 per thread
#pragma unroll
    for (int it=0; it<4; ++it){
      int idx = it*128 + tid;
      int ch = idx >> 5, c4 = idx & 31;
      float4 v = ldx(out, sob, stats, hbuf, b, ci*KC+ch, px0 + c4*4, HW);
      *(float4*)(&Xs[ch][c4*4]) = v;
    }
    // stage W chunk transposed: 64 o x 4 k-quads = 256 float4, 2 per thread
#pragma unroll
    for (int it=0; it<2; ++it){
      int idx = it*128 + tid;
      int o = idx >> 2, k4 = idx & 3;
      float4 w = *(const float4*)(pw + OW1 + o*FIN + ci*KC + k4*4);
      Ws[k4*4+0][o]=w.x; Ws[k4*4+1][o]=w.y; Ws[k4*4+2][o]=w.z; Ws[k4*4+3][o]=w.w;
    }
    __syncthreads();
#pragma unroll 2
    for (int kk=0; kk<KC; ++kk){
      float4 xa = *(const float4*)(&Xs[kk][tx*4]);
      float4 xb = *(const float4*)(&Xs[kk][(tx+16)*4]);
      float4 wa = *(const float4*)(&Ws[kk][ty*8]);
      float4 wb = *(const float4*)(&Ws[kk][ty*8+4]);
      float xv[8] = {xa.x,xa.y,xa.z,xa.w,xb.x,xb.y,xb.z,xb.w};
      float wv[8] = {wa.x,wa.y,wa.z,wa.w,wb.x,wb.y,wb.z,wb.w};
#pragma unroll
      for (int k=0;k<8;++k)
#pragma unroll
        for (int j=0;j<8;++j) acc[k][j] = fmaf(wv[k], xv[j], acc[k][j]);
    }
    __syncthreads();
  }
#pragma unroll
  for (int k=0;k<8;++k){
    int o = ty*8 + k;
    float bias = pw[OB1 + o];
    float* hp = hbuf + ((size_t)(b*64+o))*(size_t)HW + px0;
#pragma unroll
    for (int h=0; h<2; ++h){
      float4 r;
      r.x = fmaxf(acc[k][h*4+0]+bias, 0.f);
      r.y = fmaxf(acc[k][h*4+1]+bias, 0.f);
      r.z = fmaxf(acc[k][h*4+2]+bias, 0.f);
      r.w = fmaxf(acc[k][h*4+3]+bias, 0.f);
      *(float4*)(hp + (tx + h*16)*4) = r;
    }
  }
}

// z/g = [Ws|W2] @ [xn;h] + (bs+b2); out += lf*z*sigmoid(g). 128 outs, K=256.
// block (16,16)=256 thr, tile 128out x 128px; thread: 4 z-outs + their 4 g-outs, 8 px
__global__ void __launch_bounds__(256) k_gemm2n(float* __restrict__ out, const float* __restrict__ sob,
                       const float* __restrict__ stats, const float* __restrict__ p,
                       const float* __restrict__ hbuf, const float* __restrict__ lfp,
                       int HW){
  __shared__ float Xs[KC][132];
  __shared__ float Ws[KC][132];
  int b = blockIdx.y;
  int tx = threadIdx.x, ty = threadIdx.y;      // tx:0..15, ty:0..15
  int tid = ty*16 + tx;
  int px0 = blockIdx.x*TPX;
  const float* pw = p + (size_t)b*PT;
  float acc[8][8];   // [0..3]=z outs ty*4+k, [4..7]=g outs 64+ty*4+k
#pragma unroll
  for (int k=0;k<8;++k)
#pragma unroll
    for (int j=0;j<8;++j) acc[k][j]=0.f;

  for (int ci=0; ci<16; ++ci){
    // stage X chunk: 512 float4, 2 per thread
#pragma unroll
    for (int it=0; it<2; ++it){
      int idx = it*256 + tid;
      int ch = idx >> 5, c4 = idx & 31;
      float4 v = ldx(out, sob, stats, hbuf, b, ci*KC+ch, px0 + c4*4, HW);
      *(float4*)(&Xs[ch][c4*4]) = v;
    }
    // stage W chunk transposed: 128 o x 4 k-quads = 512 float4, 2 per thread
#pragma unroll
    for (int it=0; it<2; ++it){
      int idx = it*256 + tid;
      int o = idx >> 2, k4 = idx & 3;
      int i = ci*KC + k4*4;
      float4 w;
      if (i < 192) w = *(const float4*)(pw + OWS + o*FIN + i);
      else         w = *(const float4*)(pw + OW2 + o*FH + (i-192));
      Ws[k4*4+0][o]=w.x; Ws[k4*4+1][o]=w.y; Ws[k4*4+2][o]=w.z; Ws[k4*4+3][o]=w.w;
    }
    __syncthreads();
#pragma unroll 2
    for (int kk=0; kk<KC; ++kk){
      float4 xa = *(const float4*)(&Xs[kk][tx*4]);
      float4 xb = *(const float4*)(&Xs[kk][(tx+16)*4]);
      float4 wz = *(const float4*)(&Ws[kk][ty*4]);
      float4 wg = *(const float4*)(&Ws[kk][64+ty*4]);
      float xv[8] = {xa.x,xa.y,xa.z,xa.w,xb.x,xb.y,xb.z,xb.w};
      float wv[8] = {wz.x,wz.y,wz.z,wz.w,wg.x,wg.y,wg.z,wg.w};
#pragma unroll
      for (int k=0;k<8;++k)
#pragma unroll
        for (int j=0;j<8;++j) acc[k][j] = fmaf(wv[k], xv[j], acc[k][j]);
    }
    __syncthreads();
  }
  float lf = fminf(fmaxf(lfp[0], 0.001f), 1000.f);
#pragma unroll
  for (int k=0;k<4;++k){
    int o = ty*4 + k;
    float bz = pw[OB2 + o]      + pw[OBS + o];
    float bg = pw[OB2 + o + 64] + pw[OBS + o + 64];
    float* op = out + ((size_t)(b*64+o))*(size_t)HW + px0;
#pragma unroll
    for (int h=0; h<2; ++h){
      float4 ov = *(const float4*)(op + (tx + h*16)*4);
      float r[4];
#pragma unroll
      for (int j=0;j<4;++j){
        float z = acc[k][h*4+j]   + bz;
        float g = acc[k+4][h*4+j] + bg;
        r[j] = lf * z / (1.f + expf(-g));
      }
      ov.x += r[0]; ov.y += r[1]; ov.z += r[2]; ov.w += r[3];
      *(float4*)(op + (tx + h*16)*4) = ov;
    }
  }
}

// dst(2H x 2H) = gauss_blur( bilinear_up2(src) ), zero-padded blur, clamped bilinear
__global__ void k_upsample(const float* __restrict__ src, float* __restrict__ dst, int H, int lgH){
  int Hn = 2*H;
  int HWn = Hn*Hn;
  int bc = blockIdx.y;
  int opx = blockIdx.x*256 + threadIdx.x;
  const float* s = src + (size_t)bc*(size_t)(H*H);
  int oy = opx >> (lgH+1), ox = opx & (Hn-1);
  float acc = 0.f;
#pragma unroll
  for (int ky=0;ky<3;++ky){
    int yy = oy+ky-1; if (yy < 0 || yy >= Hn) continue;
    int iy = yy >> 1, ry = yy & 1;
    int y0 = ry ? iy : iy-1;
    int y1 = ry ? iy+1 : iy;
    float wy0 = ry ? 0.75f : 0.25f;
    float wy1 = 1.f - wy0;
    y0 = y0 < 0 ? 0 : y0;
    y1 = y1 > H-1 ? H-1 : y1;
#pragma unroll
    for (int kx=0;kx<3;++kx){
      int xx = ox+kx-1; if (xx < 0 || xx >= Hn) continue;
      int ix = xx >> 1, rx = xx & 1;
      int x0 = rx ? ix : ix-1;
      int x1 = rx ? ix+1 : ix;
      float wx0 = rx ? 0.75f : 0.25f;
      float wx1 = 1.f - wx0;
      x0 = x0 < 0 ? 0 : x0;
      x1 = x1 > H-1 ? H-1 : x1;
      float u = wy0*(wx0*s[y0*H+x0] + wx1*s[y0*H+x1])
              + wy1*(wx0*s[y1*H+x0] + wx1*s[y1*H+x1]);
      acc = fmaf(gk_at(ky,kx), u, acc);
    }
  }
  dst[(size_t)bc*(size_t)HWn + opx] = acc;
}

// y = W(64x64) @ in + bias, optional relu, optional += addb. block (16,8), K=64
__global__ void __launch_bounds__(128) k_lin64n(const float* __restrict__ in, const float* __restrict__ w,
                       const float* __restrict__ bias, const float* __restrict__ addb,
                       float* __restrict__ outp, int HW, int relu){
  __shared__ float Xs[KC][132];
  __shared__ float Ws[KC][68];
  int b = blockIdx.y;
  int tx = threadIdx.x, ty = threadIdx.y;
  int tid = ty*16 + tx;
  int px0 = blockIdx.x*TPX;
  float acc[8][8];
#pragma unroll
  for (int k=0;k<8;++k)
#pragma unroll
    for (int j=0;j<8;++j) acc[k][j]=0.f;

  for (int ci=0; ci<4; ++ci){
#pragma unroll
    for (int it=0; it<4; ++it){
      int idx = it*128 + tid;
      int ch = idx >> 5, c4 = idx & 31;
      float4 v = *(const float4*)(in + ((size_t)(b*64+ci*KC+ch))*(size_t)HW + px0 + c4*4);
      *(float4*)(&Xs[ch][c4*4]) = v;
    }
#pragma unroll
    for (int it=0; it<2; ++it){
      int idx = it*128 + tid;
      int o = idx >> 2, k4 = idx & 3;
      float4 wv4 = *(const float4*)(w + o*64 + ci*KC + k4*4);
      Ws[k4*4+0][o]=wv4.x; Ws[k4*4+1][o]=wv4.y; Ws[k4*4+2][o]=wv4.z; Ws[k4*4+3][o]=wv4.w;
    }
    __syncthreads();
#pragma unroll 2
    for (int kk=0; kk<KC; ++kk){
      float4 xa = *(const float4*)(&Xs[kk][tx*4]);
      float4 xb = *(const float4*)(&Xs[kk][(tx+16)*4]);
      float4 wa = *(const float4*)(&Ws[kk][ty*8]);
      float4 wb = *(const float4*)(&Ws[kk][ty*8+4]);
      float xv[8] = {xa.x,xa.y,xa.z,xa.w,xb.x,xb.y,xb.z,xb.w};
      float wv[8] = {wa.x,wa.y,wa.z,wa.w,wb.x,wb.y,wb.z,wb.w};
#pragma unroll
      for (int k=0;k<8;++k)
#pragma unroll
        for (int j=0;j<8;++j) acc[k][j] = fmaf(wv[k], xv[j], acc[k][j]);
    }
    __syncthreads();
  }
#pragma unroll
  for (int k=0;k<8;++k){
    int o = ty*8 + k;
    float bs = bias[o];
    float* op = outp + ((size_t)(b*64+o))*(size_t)HW + px0;
    const float* ap = addb ? addb + ((size_t)(b*64+o))*(size_t)HW + px0 : nullptr;
#pragma unroll
    for (int h=0; h<2; ++h){
      float4 r;
      r.x = acc[k][h*4+0]+bs; r.y = acc[k][h*4+1]+bs;
      r.z = acc[k][h*4+2]+bs; r.w = acc[k][h*4+3]+bs;
      if (relu){
        r.x=fmaxf(r.x,0.f); r.y=fmaxf(r.y,0.f); r.z=fmaxf(r.z,0.f); r.w=fmaxf(r.w,0.f);
      }
      if (ap){
        float4 a = *(const float4*)(ap + (tx+h*16)*4);
        r.x+=a.x; r.y+=a.y; r.z+=a.z; r.w+=a.w;
      }
      *(float4*)(op + (tx+h*16)*4) = r;
    }
  }
}

// y = outc_w(3x64) @ t + outc_b ; write clip(y) then raw y
__global__ void k_out3(const float* __restrict__ t, const float* __restrict__ ow,
                       const float* __restrict__ ob, float* __restrict__ dout, int HW){
  int b = blockIdx.y;
  int px4 = (blockIdx.x*256 + threadIdx.x)*4;
  float a0[4] = {0,0,0,0}, a1[4] = {0,0,0,0}, a2[4] = {0,0,0,0};
  for (int i=0;i<64;++i){
    float4 tv = *(const float4*)(t + ((size_t)(b*64+i))*(size_t)HW + px4);
    float tvv[4] = {tv.x, tv.y, tv.z, tv.w};
    float w0 = ow[i], w1 = ow[64+i], w2 = ow[128+i];
#pragma unroll
    for (int j=0;j<4;++j){
      a0[j] = fmaf(w0, tvv[j], a0[j]);
      a1[j] = fmaf(w1, tvv[j], a1[j]);
      a2[j] = fmaf(w2, tvv[j], a2[j]);
    }
  }
  size_t rawoff = (size_t)B*3*(size_t)HW;
  float bb[3] = {ob[0], ob[1], ob[2]};
  float* accs[3] = {a0, a1, a2};
#pragma unroll
  for (int c=0;c<3;++c){
    float4 raw, clp;
    float* a = accs[c];
    float y0 = a[0]+bb[c], y1 = a[1]+bb[c], y2 = a[2]+bb[c], y3 = a[3]+bb[c];
    raw.x = y0; raw.y = y1; raw.z = y2; raw.w = y3;
    clp.x = fminf(fmaxf(y0,-1.f),1.f);
    clp.y = fminf(fmaxf(y1,-1.f),1.f);
    clp.z = fminf(fmaxf(y2,-1.f),1.f);
    clp.w = fminf(fmaxf(y3,-1.f),1.f);
    size_t base = ((size_t)(b*3+c))*(size_t)HW + px4;
    *(float4*)(dout + base) = clp;
    *(float4*)(dout + rawoff + base) = raw;
  }
}

extern "C" void kernel_launch(void* const* d_in, const int* in_sizes, int n_in,
                              void* d_out, int out_size, void* d_ws, size_t ws_size,
                              hipStream_t stream) {
  const float* lat = (const float*)d_in[0];
  const float* ca  = (const float*)d_in[1];
  const float* lfp = (const float*)d_in[3];
  const float* hw  = (const float*)d_in[4];
  const float* hb  = (const float*)d_in[5];
  const float* r1w = (const float*)d_in[6];
  const float* r1b = (const float*)d_in[7];
  const float* r2w = (const float*)d_in[8];
  const float* r2b = (const float*)d_in[9];
  const float* ocw = (const float*)d_in[10];
  const float* ocb = (const float*)d_in[11];
  float* dout = (float*)d_out;

  float* ws   = (float*)d_ws;
  float* p    = ws;                                     // B*PT
  float* outA = p    + (size_t)B*PT;                    // B*64*16384
  float* outB = outA + (size_t)B*64*16384;              // B*64*16384
  float* sob  = outB + (size_t)B*64*16384;              // B*128*16384
  float* hbuf = sob  + (size_t)B*128*16384;             // B*64*16384
  float* stats= hbuf + (size_t)B*64*16384;              // B*192*2
  float* tbuf = sob;                                    // reuse after loop

  k_hyper<<<dim3((PT+255)/256), dim3(256), 0, stream>>>(lat, hw, hb, p);
  k_init<<<dim3(B*64), dim3(256), 0, stream>>>(ca, outA);

  float* cur = outA;
  float* oth = outB;
  int H = 16, lgH = 4;
  for (int c = 0; c < 16; ++c){
    int HW = H*H;
    k_sobelstats<<<dim3(B*192), dim3(256), 0, stream>>>(cur, sob, stats, H, lgH, HW);
    dim3 g(HW/TPX, B);
    k_gemm1n<<<g, dim3(16,8),  0, stream>>>(cur, sob, stats, p, hbuf, HW);
    k_gemm2n<<<g, dim3(16,16), 0, stream>>>(cur, sob, stats, p, hbuf, lfp, HW);
    if (c < 15 && (c & 3) == 3){
      k_upsample<<<dim3((HW*4)/256, B*64), dim3(256), 0, stream>>>(cur, oth, H, lgH);
      float* tmp = cur; cur = oth; oth = tmp;
      H *= 2; lgH += 1;
    }
  }
  int HW = H*H;  // 16384
  dim3 g(HW/TPX, B);
  k_lin64n<<<g, dim3(16,8), 0, stream>>>(cur, r1w, r1b, nullptr, hbuf, HW, 1);
  k_lin64n<<<g, dim3(16,8), 0, stream>>>(hbuf, r2w, r2b, cur, tbuf, HW, 0);
  k_out3<<<dim3(HW/1024, B), dim3(256), 0, stream>>>(tbuf, ocw, ocb, dout, HW);
}

// Round 3
// 1848.413 us; speedup vs baseline: 4.7042x; 1.3727x over previous
//
#include <hip/hip_runtime.h>
#include <math.h>

#define B 8
#define LATD 512
#define PT 45376
#define FIN 192
#define FH 64
#define OW1 0
#define OB1 12288
#define OW2 12352
#define OB2 20544
#define OWS 20672
#define OBS 45248
#define TPX 128   // pixel tile per block
#define KC 16     // K chunk

__device__ __forceinline__ float gk_at(int ky, int kx){
  const float a = 0.60653065971263342f;
  const float inv = 1.0f / ((1.0f + 2.0f*a) * (1.0f + 2.0f*a));
  float wy = (ky==1) ? 1.0f : a;
  float wx = (kx==1) ? 1.0f : a;
  return wy * wx * inv;
}

// p[b][j] = sum_k lat[b][k] * hyper_w[k][j] + hyper_b[j]
__global__ void k_hyper(const float* __restrict__ lat, const float* __restrict__ hw,
                        const float* __restrict__ hb, float* __restrict__ p){
  __shared__ float slat[B*LATD];
  for (int idx = threadIdx.x; idx < B*LATD; idx += 256) slat[idx] = lat[idx];
  __syncthreads();
  int j = blockIdx.x*256 + threadIdx.x;
  if (j >= PT) return;
  float acc[B];
#pragma unroll
  for (int b=0;b<B;++b) acc[b]=0.f;
  for (int k=0;k<LATD;++k){
    float w = hw[(size_t)k*PT + j];
#pragma unroll
    for (int b=0;b<B;++b) acc[b] = fmaf(slat[b*LATD+k], w, acc[b]);
  }
  float bias = hb[j];
#pragma unroll
  for (int b=0;b<B;++b) p[(size_t)b*PT + j] = acc[b] + bias;
}

// out = gauss_blur(ca_noise) at 16x16  (inst_norm(broadcast(seed)) == 0 exactly)
__global__ void k_init(const float* __restrict__ noise, float* __restrict__ out){
  int bc = blockIdx.x;
  int t = threadIdx.x;
  int y = t >> 4, x = t & 15;
  const float* src = noise + (size_t)bc*256;
  float acc = 0.f;
#pragma unroll
  for (int ky=0;ky<3;++ky){
    int yy = y+ky-1; if (yy < 0 || yy > 15) continue;
#pragma unroll
    for (int kx=0;kx<3;++kx){
      int xx = x+kx-1; if (xx < 0 || xx > 15) continue;
      acc = fmaf(gk_at(ky,kx), src[yy*16+xx], acc);
    }
  }
  out[(size_t)bc*256 + t] = acc;
}

// sobel channels + per-(b,c) (c=-m*r, r=rstd) for all 192 z-channels
__global__ void k_sobelstats(const float* __restrict__ out, float* __restrict__ sob,
                             float* __restrict__ stats, int H, int lgH, int HW){
  int bc = blockIdx.x; int b = bc/192, c = bc - b*192;
  int t = threadIdx.x;
  float s = 0.f, ss = 0.f;
  if (c < 64){
    const float* src = out + ((size_t)b*64 + c)*(size_t)HW;
    for (int px = t; px < HW; px += 256){ float v = src[px]; s += v; ss = fmaf(v,v,ss); }
  } else {
    int cc = (c-64) & 63;
    int isY = (c >= 128);
    const float* src = out + ((size_t)b*64 + cc)*(size_t)HW;
    float* dst = sob + ((size_t)b*128 + (c-64))*(size_t)HW;
    for (int px = t; px < HW; px += 256){
      int y = px >> lgH, x = px & (H-1);
      float acc = 0.f;
#pragma unroll
      for (int ky=0;ky<3;++ky){
        int yy = y+ky-1; if (yy < 0 || yy >= H) continue;
        float vy = (ky==1)?2.f:1.f, dy = (float)(ky-1);
#pragma unroll
        for (int kx=0;kx<3;++kx){
          int xx = x+kx-1; if (xx < 0 || xx >= H) continue;
          float vx = (kx==1)?2.f:1.f, dx = (float)(kx-1);
          float w = isY ? dy*vx : vy*dx;
          if (w == 0.f) continue;
          acc = fmaf(w*0.125f, src[yy*H+xx], acc);
        }
      }
      dst[px] = acc; s += acc; ss = fmaf(acc,acc,ss);
    }
  }
  __shared__ float r1[256], r2[256];
  r1[t] = s; r2[t] = ss; __syncthreads();
  for (int off=128; off>0; off>>=1){
    if (t < off){ r1[t] += r1[t+off]; r2[t] += r2[t+off]; }
    __syncthreads();
  }
  if (t == 0){
    float inv = 1.0f/(float)HW;
    float m = r1[0]*inv;
    float var = fmaxf(r2[0]*inv - m*m, 0.f);
    float r = 1.0f/sqrtf(var + 1e-5f);
    stats[bc*2]   = -m*r;   // c:  xn = fma(x, r, c)
    stats[bc*2+1] = r;
  }
}

// load one float4 of normalized x: channels [out(64) ; sob(128)]
__device__ __forceinline__ float4 ldx(const float* __restrict__ out, const float* __restrict__ sob,
                                      const float* __restrict__ stats,
                                      int b, int i, int off, int HW){
  const float* src = (i < 64) ? out + ((size_t)(b*64+i))*(size_t)HW
                              : sob + ((size_t)(b*128+(i-64)))*(size_t)HW;
  float4 v = *(const float4*)(src + off);
  float c = stats[(b*192+i)*2], r = stats[(b*192+i)*2+1];
  v.x = fmaf(v.x, r, c); v.y = fmaf(v.y, r, c);
  v.z = fmaf(v.z, r, c); v.w = fmaf(v.w, r, c);
  return v;
}

// Fused dyna block: h = relu(W1@xn+b1); z/g = Ws@xn + W2@h + biases; out += lf*z*sigmoid(g)
// block (16,16)=256 thr; tile: all 128 z/g outs + all 64 h outs x 128 px
__global__ void __launch_bounds__(256) k_dyna(float* __restrict__ out, const float* __restrict__ sob,
                       const float* __restrict__ stats, const float* __restrict__ p,
                       const float* __restrict__ lfp, int HW){
  __shared__ float Xs[KC][132];
  __shared__ float Wzs[KC][132];   // [k][o] for z(0..63) and g(64..127)
  __shared__ float W1s[KC][68];    // [k][o] for h
  __shared__ float Hs[64][132];    // h values [k][px]
  int b = blockIdx.y;
  int tx = threadIdx.x, ty = threadIdx.y;
  int tid = ty*16 + tx;
  int px0 = blockIdx.x*TPX;
  const float* pw = p + (size_t)b*PT;

  float az[4][8], ag[4][8], ah[4][8];
#pragma unroll
  for (int k=0;k<4;++k)
#pragma unroll
    for (int j=0;j<8;++j){ az[k][j]=0.f; ag[k][j]=0.f; ah[k][j]=0.f; }

  // prefetch register decode
  const int xch0 = tid>>5,        xc4 = tid&31;
  const int xch1 = 8 + (tid>>5);
  const int wo0  = tid>>2,        wk  = tid&3;
  const int wo1  = 64 + (tid>>2);

  float4 vx0, vx1, vz0, vz1, v10;

  // ---- phase A: K = 0..191 (x inputs), 12 chunks, software-pipelined ----
  {
    int ci = 0;
    vx0 = ldx(out, sob, stats, b, ci*KC+xch0, px0 + xc4*4, HW);
    vx1 = ldx(out, sob, stats, b, ci*KC+xch1, px0 + xc4*4, HW);
    vz0 = *(const float4*)(pw + OWS + wo0*FIN + ci*KC + wk*4);
    vz1 = *(const float4*)(pw + OWS + wo1*FIN + ci*KC + wk*4);
    v10 = *(const float4*)(pw + OW1 + wo0*FIN + ci*KC + wk*4);
  }
  for (int ci=0; ci<12; ++ci){
    __syncthreads();               // previous compute done; LDS safe
    *(float4*)(&Xs[xch0][xc4*4]) = vx0;
    *(float4*)(&Xs[xch1][xc4*4]) = vx1;
    Wzs[wk*4+0][wo0]=vz0.x; Wzs[wk*4+1][wo0]=vz0.y; Wzs[wk*4+2][wo0]=vz0.z; Wzs[wk*4+3][wo0]=vz0.w;
    Wzs[wk*4+0][wo1]=vz1.x; Wzs[wk*4+1][wo1]=vz1.y; Wzs[wk*4+2][wo1]=vz1.z; Wzs[wk*4+3][wo1]=vz1.w;
    W1s[wk*4+0][wo0]=v10.x; W1s[wk*4+1][wo0]=v10.y; W1s[wk*4+2][wo0]=v10.z; W1s[wk*4+3][wo0]=v10.w;
    if (ci+1 < 12){                // issue next chunk's loads; they fly during compute
      int cn = ci+1;
      vx0 = ldx(out, sob, stats, b, cn*KC+xch0, px0 + xc4*4, HW);
      vx1 = ldx(out, sob, stats, b, cn*KC+xch1, px0 + xc4*4, HW);
      vz0 = *(const float4*)(pw + OWS + wo0*FIN + cn*KC + wk*4);
      vz1 = *(const float4*)(pw + OWS + wo1*FIN + cn*KC + wk*4);
      v10 = *(const float4*)(pw + OW1 + wo0*FIN + cn*KC + wk*4);
    }
    __syncthreads();               // staging visible
#pragma unroll 4
    for (int kk=0; kk<KC; ++kk){
      float4 xa = *(const float4*)(&Xs[kk][tx*4]);
      float4 xb = *(const float4*)(&Xs[kk][(tx+16)*4]);
      float4 wz4 = *(const float4*)(&Wzs[kk][ty*4]);
      float4 wg4 = *(const float4*)(&Wzs[kk][64+ty*4]);
      float4 w14 = *(const float4*)(&W1s[kk][ty*4]);
      float xv[8] = {xa.x,xa.y,xa.z,xa.w,xb.x,xb.y,xb.z,xb.w};
      float wzv[4]= {wz4.x,wz4.y,wz4.z,wz4.w};
      float wgv[4]= {wg4.x,wg4.y,wg4.z,wg4.w};
      float w1v[4]= {w14.x,w14.y,w14.z,w14.w};
#pragma unroll
      for (int k=0;k<4;++k)
#pragma unroll
        for (int j=0;j<8;++j){
          az[k][j] = fmaf(wzv[k], xv[j], az[k][j]);
          ag[k][j] = fmaf(wgv[k], xv[j], ag[k][j]);
          ah[k][j] = fmaf(w1v[k], xv[j], ah[k][j]);
        }
    }
  }

  // prefetch first W2 chunk while finishing h
  vz0 = *(const float4*)(pw + OW2 + wo0*FH + wk*4);
  vz1 = *(const float4*)(pw + OW2 + wo1*FH + wk*4);

  // ---- phase B: h = relu(ah + b1) -> Hs[k][px] ----
#pragma unroll
  for (int k=0;k<4;++k){
    float b1 = pw[OB1 + ty*4 + k];
#pragma unroll
    for (int h=0; h<2; ++h){
      float4 r;
      r.x = fmaxf(ah[k][h*4+0]+b1, 0.f);
      r.y = fmaxf(ah[k][h*4+1]+b1, 0.f);
      r.z = fmaxf(ah[k][h*4+2]+b1, 0.f);
      r.w = fmaxf(ah[k][h*4+3]+b1, 0.f);
      *(float4*)(&Hs[ty*4+k][(tx+h*16)*4]) = r;
    }
  }

  // ---- phase C: K = 192..255 (h from LDS), 4 chunks ----
  for (int ci=0; ci<4; ++ci){
    __syncthreads();   // ci=0: Hs writes visible + Wzs free (all waves past phase A)
    Wzs[wk*4+0][wo0]=vz0.x; Wzs[wk*4+1][wo0]=vz0.y; Wzs[wk*4+2][wo0]=vz0.z; Wzs[wk*4+3][wo0]=vz0.w;
    Wzs[wk*4+0][wo1]=vz1.x; Wzs[wk*4+1][wo1]=vz1.y; Wzs[wk*4+2][wo1]=vz1.z; Wzs[wk*4+3][wo1]=vz1.w;
    if (ci+1 < 4){
      int cn = ci+1;
      vz0 = *(const float4*)(pw + OW2 + wo0*FH + cn*KC + wk*4);
      vz1 = *(const float4*)(pw + OW2 + wo1*FH + cn*KC + wk*4);
    }
    __syncthreads();
#pragma unroll 4
    for (int kk=0; kk<KC; ++kk){
      float4 xa = *(const float4*)(&Hs[ci*KC+kk][tx*4]);
      float4 xb = *(const float4*)(&Hs[ci*KC+kk][(tx+16)*4]);
      float4 wz4 = *(const float4*)(&Wzs[kk][ty*4]);
      float4 wg4 = *(const float4*)(&Wzs[kk][64+ty*4]);
      float xv[8] = {xa.x,xa.y,xa.z,xa.w,xb.x,xb.y,xb.z,xb.w};
      float wzv[4]= {wz4.x,wz4.y,wz4.z,wz4.w};
      float wgv[4]= {wg4.x,wg4.y,wg4.z,wg4.w};
#pragma unroll
      for (int k=0;k<4;++k)
#pragma unroll
        for (int j=0;j<8;++j){
          az[k][j] = fmaf(wzv[k], xv[j], az[k][j]);
          ag[k][j] = fmaf(wgv[k], xv[j], ag[k][j]);
        }
    }
  }

  // ---- epilogue: out += lf * z * sigmoid(g) ----
  float lf = fminf(fmaxf(lfp[0], 0.001f), 1000.f);
#pragma unroll
  for (int k=0;k<4;++k){
    int o = ty*4 + k;
    float bz = pw[OB2 + o]      + pw[OBS + o];
    float bg = pw[OB2 + o + 64] + pw[OBS + o + 64];
    float* op = out + ((size_t)(b*64+o))*(size_t)HW + px0;
#pragma unroll
    for (int h=0; h<2; ++h){
      float4 ov = *(const float4*)(op + (tx + h*16)*4);
      float r[4];
#pragma unroll
      for (int j=0;j<4;++j){
        float z = az[k][h*4+j] + bz;
        float g = ag[k][h*4+j] + bg;
        r[j] = lf * z / (1.f + expf(-g));
      }
      ov.x += r[0]; ov.y += r[1]; ov.z += r[2]; ov.w += r[3];
      *(float4*)(op + (tx + h*16)*4) = ov;
    }
  }
}

// dst(2H x 2H) = gauss_blur( bilinear_up2(src) ), zero-padded blur, clamped bilinear
__global__ void k_upsample(const float* __restrict__ src, float* __restrict__ dst, int H, int lgH){
  int Hn = 2*H;
  int HWn = Hn*Hn;
  int bc = blockIdx.y;
  int opx = blockIdx.x*256 + threadIdx.x;
  const float* s = src + (size_t)bc*(size_t)(H*H);
  int oy = opx >> (lgH+1), ox = opx & (Hn-1);
  float acc = 0.f;
#pragma unroll
  for (int ky=0;ky<3;++ky){
    int yy = oy+ky-1; if (yy < 0 || yy >= Hn) continue;
    int iy = yy >> 1, ry = yy & 1;
    int y0 = ry ? iy : iy-1;
    int y1 = ry ? iy+1 : iy;
    float wy0 = ry ? 0.75f : 0.25f;
    float wy1 = 1.f - wy0;
    y0 = y0 < 0 ? 0 : y0;
    y1 = y1 > H-1 ? H-1 : y1;
#pragma unroll
    for (int kx=0;kx<3;++kx){
      int xx = ox+kx-1; if (xx < 0 || xx >= Hn) continue;
      int ix = xx >> 1, rx = xx & 1;
      int x0 = rx ? ix : ix-1;
      int x1 = rx ? ix+1 : ix;
      float wx0 = rx ? 0.75f : 0.25f;
      float wx1 = 1.f - wx0;
      x0 = x0 < 0 ? 0 : x0;
      x1 = x1 > H-1 ? H-1 : x1;
      float u = wy0*(wx0*s[y0*H+x0] + wx1*s[y0*H+x1])
              + wy1*(wx0*s[y1*H+x0] + wx1*s[y1*H+x1]);
      acc = fmaf(gk_at(ky,kx), u, acc);
    }
  }
  dst[(size_t)bc*(size_t)HWn + opx] = acc;
}

// Fused epilogue: h'=relu(r1w@t+r1b); t2 = t + r2w@h'+r2b; y = ocw@t2+ocb; write clip(y),raw(y)
__global__ void __launch_bounds__(256) k_final(const float* __restrict__ t,
    const float* __restrict__ r1w, const float* __restrict__ r1b,
    const float* __restrict__ r2w, const float* __restrict__ r2b,
    const float* __restrict__ ocw, const float* __restrict__ ocb,
    float* __restrict__ dout, int HW){
  __shared__ float Ts[64][132];
  __shared__ float Hs[64][132];
  __shared__ float Wb[64][68];
  int b = blockIdx.y;
  int tx = threadIdx.x, ty = threadIdx.y;
  int tid = ty*16 + tx;
  int px0 = blockIdx.x*TPX;

  // stage full t tile + r1w^T
#pragma unroll
  for (int it=0; it<8; ++it){
    int idx = it*256 + tid;
    int ch = idx>>5, c4 = idx&31;
    *(float4*)(&Ts[ch][c4*4]) = *(const float4*)(t + ((size_t)(b*64+ch))*(size_t)HW + px0 + c4*4);
  }
#pragma unroll
  for (int it=0; it<4; ++it){
    int idx = it*256 + tid;
    int o = idx>>4, k4 = idx&15;
    float4 w = *(const float4*)(r1w + o*64 + k4*4);
    Wb[k4*4+0][o]=w.x; Wb[k4*4+1][o]=w.y; Wb[k4*4+2][o]=w.z; Wb[k4*4+3][o]=w.w;
  }
  __syncthreads();

  float acc[4][8];
#pragma unroll
  for (int k=0;k<4;++k)
#pragma unroll
    for (int j=0;j<8;++j) acc[k][j]=0.f;
#pragma unroll 4
  for (int kk=0; kk<64; ++kk){
    float4 xa = *(const float4*)(&Ts[kk][tx*4]);
    float4 xb = *(const float4*)(&Ts[kk][(tx+16)*4]);
    float4 w4 = *(const float4*)(&Wb[kk][ty*4]);
    float xv[8]={xa.x,xa.y,xa.z,xa.w,xb.x,xb.y,xb.z,xb.w};
    float wv[4]={w4.x,w4.y,w4.z,w4.w};
#pragma unroll
    for (int k=0;k<4;++k)
#pragma unroll
      for (int j=0;j<8;++j) acc[k][j] = fmaf(wv[k], xv[j], acc[k][j]);
  }
  __syncthreads();   // compute done; safe to overwrite Wb, write Hs

#pragma unroll
  for (int k=0;k<4;++k){
    float bs = r1b[ty*4+k];
#pragma unroll
    for (int h=0; h<2; ++h){
      float4 r;
      r.x = fmaxf(acc[k][h*4+0]+bs, 0.f);
      r.y = fmaxf(acc[k][h*4+1]+bs, 0.f);
      r.z = fmaxf(acc[k][h*4+2]+bs, 0.f);
      r.w = fmaxf(acc[k][h*4+3]+bs, 0.f);
      *(float4*)(&Hs[ty*4+k][(tx+h*16)*4]) = r;
    }
  }
#pragma unroll
  for (int it=0; it<4; ++it){
    int idx = it*256 + tid;
    int o = idx>>4, k4 = idx&15;
    float4 w = *(const float4*)(r2w + o*64 + k4*4);
    Wb[k4*4+0][o]=w.x; Wb[k4*4+1][o]=w.y; Wb[k4*4+2][o]=w.z; Wb[k4*4+3][o]=w.w;
  }
  __syncthreads();

#pragma unroll
  for (int k=0;k<4;++k)
#pragma unroll
    for (int j=0;j<8;++j) acc[k][j]=0.f;
#pragma unroll 4
  for (int kk=0; kk<64; ++kk){
    float4 xa = *(const float4*)(&Hs[kk][tx*4]);
    float4 xb = *(const float4*)(&Hs[kk][(tx+16)*4]);
    float4 w4 = *(const float4*)(&Wb[kk][ty*4]);
    float xv[8]={xa.x,xa.y,xa.z,xa.w,xb.x,xb.y,xb.z,xb.w};
    float wv[4]={w4.x,w4.y,w4.z,w4.w};
#pragma unroll
    for (int k=0;k<4;++k)
#pragma unroll
      for (int j=0;j<8;++j) acc[k][j] = fmaf(wv[k], xv[j], acc[k][j]);
  }
  // t2 = t + r + b2, written back to own Ts elements (no reader until barrier)
#pragma unroll
  for (int k=0;k<4;++k){
    int o = ty*4 + k;
    float bs = r2b[o];
#pragma unroll
    for (int h=0; h<2; ++h){
      float4 tv = *(const float4*)(&Ts[o][(tx+h*16)*4]);
      tv.x += acc[k][h*4+0]+bs; tv.y += acc[k][h*4+1]+bs;
      tv.z += acc[k][h*4+2]+bs; tv.w += acc[k][h*4+3]+bs;
      *(float4*)(&Ts[o][(tx+h*16)*4]) = tv;
    }
  }
  __syncthreads();   // t2 visible, Wb free
  if (tid < 192){
    int c = tid>>6, kk = tid&63;
    Wb[kk][c] = ocw[c*64+kk];
  }
  __syncthreads();

  if (tid < 128){
    float a0=0.f, a1=0.f, a2=0.f;
#pragma unroll 4
    for (int kk=0; kk<64; ++kk){
      float x = Ts[kk][tid];
      a0 = fmaf(x, Wb[kk][0], a0);
      a1 = fmaf(x, Wb[kk][1], a1);
      a2 = fmaf(x, Wb[kk][2], a2);
    }
    size_t rawoff = (size_t)B*3*(size_t)HW;
    float y[3] = {a0+ocb[0], a1+ocb[1], a2+ocb[2]};
    int px = px0 + tid;
#pragma unroll
    for (int c=0;c<3;++c){
      size_t base = ((size_t)(b*3+c))*(size_t)HW + px;
      dout[base] = fminf(fmaxf(y[c],-1.f),1.f);
      dout[rawoff + base] = y[c];
    }
  }
}

extern "C" void kernel_launch(void* const* d_in, const int* in_sizes, int n_in,
                              void* d_out, int out_size, void* d_ws, size_t ws_size,
                              hipStream_t stream) {
  const float* lat = (const float*)d_in[0];
  const float* ca  = (const float*)d_in[1];
  const float* lfp = (const float*)d_in[3];
  const float* hw  = (const float*)d_in[4];
  const float* hb  = (const float*)d_in[5];
  const float* r1w = (const float*)d_in[6];
  const float* r1b = (const float*)d_in[7];
  const float* r2w = (const float*)d_in[8];
  const float* r2b = (const float*)d_in[9];
  const float* ocw = (const float*)d_in[10];
  const float* ocb = (const float*)d_in[11];
  float* dout = (float*)d_out;

  float* ws   = (float*)d_ws;
  float* p    = ws;                                     // B*PT
  float* outA = p    + (size_t)B*PT;                    // B*64*16384
  float* outB = outA + (size_t)B*64*16384;              // B*64*16384
  float* sob  = outB + (size_t)B*64*16384;              // B*128*16384
  float* stats= sob  + (size_t)B*128*16384;             // B*192*2

  k_hyper<<<dim3((PT+255)/256), dim3(256), 0, stream>>>(lat, hw, hb, p);
  k_init<<<dim3(B*64), dim3(256), 0, stream>>>(ca, outA);

  float* cur = outA;
  float* oth = outB;
  int H = 16, lgH = 4;
  for (int c = 0; c < 16; ++c){
    int HW = H*H;
    k_sobelstats<<<dim3(B*192), dim3(256), 0, stream>>>(cur, sob, stats, H, lgH, HW);
    k_dyna<<<dim3(HW/TPX, B), dim3(16,16), 0, stream>>>(cur, sob, stats, p, lfp, HW);
    if (c < 15 && (c & 3) == 3){
      k_upsample<<<dim3((HW*4)/256, B*64), dim3(256), 0, stream>>>(cur, oth, H, lgH);
      float* tmp = cur; cur = oth; oth = tmp;
      H *= 2; lgH += 1;
    }
  }
  int HW = H*H;  // 16384
  k_final<<<dim3(HW/TPX, B), dim3(16,16), 0, stream>>>(cur, r1w, r1b, r2w, r2b, ocw, ocb, dout, HW);
}

// Round 4
// 1516.287 us; speedup vs baseline: 5.7346x; 1.2190x over previous
//
#include <hip/hip_runtime.h>
#include <math.h>

#define B 8
#define LATD 512
#define PT 45376
#define FIN 192
#define FH 64
#define OW1 0
#define OB1 12288
#define OW2 12352
#define OB2 20544
#define OWS 20672
#define OBS 45248
#define TPX 128   // pixel tile per block
#define KC 16     // K chunk

__device__ __forceinline__ float gk_at(int ky, int kx){
  const float a = 0.60653065971263342f;
  const float inv = 1.0f / ((1.0f + 2.0f*a) * (1.0f + 2.0f*a));
  float wy = (ky==1) ? 1.0f : a;
  float wx = (kx==1) ? 1.0f : a;
  return wy * wx * inv;
}

// p[b][j] = sum_k lat[b][k] * hyper_w[k][j] + hyper_b[j]
__global__ void k_hyper(const float* __restrict__ lat, const float* __restrict__ hw,
                        const float* __restrict__ hb, float* __restrict__ p){
  __shared__ float slat[B*LATD];
  for (int idx = threadIdx.x; idx < B*LATD; idx += 256) slat[idx] = lat[idx];
  __syncthreads();
  int j = blockIdx.x*256 + threadIdx.x;
  if (j >= PT) return;
  float acc[B];
#pragma unroll
  for (int b=0;b<B;++b) acc[b]=0.f;
  for (int k=0;k<LATD;++k){
    float w = hw[(size_t)k*PT + j];
#pragma unroll
    for (int b=0;b<B;++b) acc[b] = fmaf(slat[b*LATD+k], w, acc[b]);
  }
  float bias = hb[j];
#pragma unroll
  for (int b=0;b<B;++b) p[(size_t)b*PT + j] = acc[b] + bias;
}

// out = gauss_blur(ca_noise) at 16x16  (inst_norm(broadcast(seed)) == 0 exactly)
__global__ void k_init(const float* __restrict__ noise, float* __restrict__ out){
  int bc = blockIdx.x;
  int t = threadIdx.x;
  int y = t >> 4, x = t & 15;
  const float* src = noise + (size_t)bc*256;
  float acc = 0.f;
#pragma unroll
  for (int ky=0;ky<3;++ky){
    int yy = y+ky-1; if (yy < 0 || yy > 15) continue;
#pragma unroll
    for (int kx=0;kx<3;++kx){
      int xx = x+kx-1; if (xx < 0 || xx > 15) continue;
      acc = fmaf(gk_at(ky,kx), src[yy*16+xx], acc);
    }
  }
  out[(size_t)bc*256 + t] = acc;
}

// Fused sobel + stats: one block per (b, c<64). Reads channel once, writes dx,dy,
// and stats (c=-m*r, r) for out-channel c, sobx channel 64+c, soby channel 128+c.
__global__ void __launch_bounds__(256) k_sobstat(const float* __restrict__ out, float* __restrict__ sob,
                    float* __restrict__ stats, int H, int lgH, int HW){
  int bc = blockIdx.x; int b = bc >> 6, c = bc & 63;
  int t = threadIdx.x;
  const float* src = out + ((size_t)(b*64+c))*(size_t)HW;
  float* dxp = sob + ((size_t)(b*128 + c))*(size_t)HW;
  float* dyp = sob + ((size_t)(b*128 + 64 + c))*(size_t)HW;
  float s0=0.f,q0=0.f,sx=0.f,qx=0.f,sy=0.f,qy=0.f;
  for (int px = t*4; px < HW; px += 1024){
    int y = px >> lgH, x = px & (H-1);
    float rm[6], rc[6], rp[6];
    float4 v = *(const float4*)(src + px);
    rc[1]=v.x; rc[2]=v.y; rc[3]=v.z; rc[4]=v.w;
    rc[0] = (x>0)     ? src[px-1] : 0.f;
    rc[5] = (x+4 < H) ? src[px+4] : 0.f;
    s0 += v.x+v.y+v.z+v.w;
    q0 += v.x*v.x+v.y*v.y+v.z*v.z+v.w*v.w;
    if (y > 0){
      const float* r = src + px - H;
      float4 u = *(const float4*)r;
      rm[1]=u.x; rm[2]=u.y; rm[3]=u.z; rm[4]=u.w;
      rm[0] = (x>0)     ? r[-1] : 0.f;
      rm[5] = (x+4 < H) ? r[4]  : 0.f;
    } else { rm[0]=rm[1]=rm[2]=rm[3]=rm[4]=rm[5]=0.f; }
    if (y+1 < H){
      const float* r = src + px + H;
      float4 u = *(const float4*)r;
      rp[1]=u.x; rp[2]=u.y; rp[3]=u.z; rp[4]=u.w;
      rp[0] = (x>0)     ? r[-1] : 0.f;
      rp[5] = (x+4 < H) ? r[4]  : 0.f;
    } else { rp[0]=rp[1]=rp[2]=rp[3]=rp[4]=rp[5]=0.f; }
    float dxv[4], dyv[4];
#pragma unroll
    for (int j=0;j<4;++j){
      dxv[j] = ((rm[j+2]-rm[j]) + 2.f*(rc[j+2]-rc[j]) + (rp[j+2]-rp[j])) * 0.125f;
      dyv[j] = ((rp[j] + 2.f*rp[j+1] + rp[j+2]) - (rm[j] + 2.f*rm[j+1] + rm[j+2])) * 0.125f;
      sx += dxv[j]; qx = fmaf(dxv[j],dxv[j],qx);
      sy += dyv[j]; qy = fmaf(dyv[j],dyv[j],qy);
    }
    float4 o1; o1.x=dxv[0]; o1.y=dxv[1]; o1.z=dxv[2]; o1.w=dxv[3];
    float4 o2; o2.x=dyv[0]; o2.y=dyv[1]; o2.z=dyv[2]; o2.w=dyv[3];
    *(float4*)(dxp + px) = o1;
    *(float4*)(dyp + px) = o2;
  }
  // reduce 3 stat pairs
  float vals[6] = {s0,q0,sx,qx,sy,qy};
  __shared__ float rbuf[6][4];
  int lane = t & 63, wid = t >> 6;
#pragma unroll
  for (int i=0;i<6;++i){
    float v = vals[i];
#pragma unroll
    for (int off=32; off; off>>=1) v += __shfl_down(v, off, 64);
    if (lane==0) rbuf[i][wid] = v;
  }
  __syncthreads();
  if (t < 3){
    float s = rbuf[t*2][0]+rbuf[t*2][1]+rbuf[t*2][2]+rbuf[t*2][3];
    float q = rbuf[t*2+1][0]+rbuf[t*2+1][1]+rbuf[t*2+1][2]+rbuf[t*2+1][3];
    float inv = 1.0f/(float)HW;
    float m = s*inv;
    float var = fmaxf(q*inv - m*m, 0.f);
    float r = 1.0f/sqrtf(var + 1e-5f);
    int ch = b*192 + c + t*64;
    stats[ch*2]   = -m*r;
    stats[ch*2+1] = r;
  }
}

// load one float4 of normalized x: channels [out(64) ; sob(128)]
__device__ __forceinline__ float4 ldx(const float* __restrict__ out, const float* __restrict__ sob,
                                      const float* __restrict__ stats,
                                      int b, int i, int off, int HW){
  const float* src = (i < 64) ? out + ((size_t)(b*64+i))*(size_t)HW
                              : sob + ((size_t)(b*128+(i-64)))*(size_t)HW;
  float4 v = *(const float4*)(src + off);
  float c = stats[(b*192+i)*2], r = stats[(b*192+i)*2+1];
  v.x = fmaf(v.x, r, c); v.y = fmaf(v.y, r, c);
  v.z = fmaf(v.z, r, c); v.w = fmaf(v.w, r, c);
  return v;
}

// Fused dyna block with union LDS (41.25 KB -> 3 blocks/CU).
// bufA: phase A = Xs[16][132] + W1s[16][68]; phase C = Hs[64][132] (aliased).
// bufB: Wzs[16][132] (z+g weights, then W2).
#define XS(k,p)  bufA[(k)*132 + (p)]
#define W1S(k,o) bufA[2112 + (k)*68 + (o)]
#define HS(k,p)  bufA[(k)*132 + (p)]
#define WZS(k,o) bufB[(k)*132 + (o)]
__global__ void __launch_bounds__(256, 3) k_dyna(float* __restrict__ out, const float* __restrict__ sob,
                       const float* __restrict__ stats, const float* __restrict__ p,
                       const float* __restrict__ lfp, int HW){
  __shared__ float bufA[8448];
  __shared__ float bufB[2112];
  int b = blockIdx.y;
  int tx = threadIdx.x, ty = threadIdx.y;
  int tid = ty*16 + tx;
  int px0 = blockIdx.x*TPX;
  const float* pw = p + (size_t)b*PT;

  float az[4][8], ag[4][8], ah[4][8];
#pragma unroll
  for (int k=0;k<4;++k)
#pragma unroll
    for (int j=0;j<8;++j){ az[k][j]=0.f; ag[k][j]=0.f; ah[k][j]=0.f; }

  const int xch0 = tid>>5,        xc4 = tid&31;
  const int xch1 = 8 + (tid>>5);
  const int wo0  = tid>>2,        wk  = tid&3;
  const int wo1  = 64 + (tid>>2);

  float4 vx0, vx1, vz0, vz1, v10;

  // ---- phase A: K = 0..191 (x inputs), 12 chunks, software-pipelined ----
  vx0 = ldx(out, sob, stats, b, xch0, px0 + xc4*4, HW);
  vx1 = ldx(out, sob, stats, b, xch1, px0 + xc4*4, HW);
  vz0 = *(const float4*)(pw + OWS + wo0*FIN + wk*4);
  vz1 = *(const float4*)(pw + OWS + wo1*FIN + wk*4);
  v10 = *(const float4*)(pw + OW1 + wo0*FIN + wk*4);

  for (int ci=0; ci<12; ++ci){
    __syncthreads();               // previous compute done; LDS safe
    *(float4*)(&XS(xch0, xc4*4)) = vx0;
    *(float4*)(&XS(xch1, xc4*4)) = vx1;
    WZS(wk*4+0,wo0)=vz0.x; WZS(wk*4+1,wo0)=vz0.y; WZS(wk*4+2,wo0)=vz0.z; WZS(wk*4+3,wo0)=vz0.w;
    WZS(wk*4+0,wo1)=vz1.x; WZS(wk*4+1,wo1)=vz1.y; WZS(wk*4+2,wo1)=vz1.z; WZS(wk*4+3,wo1)=vz1.w;
    W1S(wk*4+0,wo0)=v10.x; W1S(wk*4+1,wo0)=v10.y; W1S(wk*4+2,wo0)=v10.z; W1S(wk*4+3,wo0)=v10.w;
    if (ci+1 < 12){
      int cn = ci+1;
      vx0 = ldx(out, sob, stats, b, cn*KC+xch0, px0 + xc4*4, HW);
      vx1 = ldx(out, sob, stats, b, cn*KC+xch1, px0 + xc4*4, HW);
      vz0 = *(const float4*)(pw + OWS + wo0*FIN + cn*KC + wk*4);
      vz1 = *(const float4*)(pw + OWS + wo1*FIN + cn*KC + wk*4);
      v10 = *(const float4*)(pw + OW1 + wo0*FIN + cn*KC + wk*4);
    }
    __syncthreads();               // staging visible
#pragma unroll 4
    for (int kk=0; kk<KC; ++kk){
      float4 xa = *(const float4*)(&XS(kk, tx*4));
      float4 xb = *(const float4*)(&XS(kk, (tx+16)*4));
      float4 wz4 = *(const float4*)(&WZS(kk, ty*4));
      float4 wg4 = *(const float4*)(&WZS(kk, 64+ty*4));
      float4 w14 = *(const float4*)(&W1S(kk, ty*4));
      float xv[8] = {xa.x,xa.y,xa.z,xa.w,xb.x,xb.y,xb.z,xb.w};
      float wzv[4]= {wz4.x,wz4.y,wz4.z,wz4.w};
      float wgv[4]= {wg4.x,wg4.y,wg4.z,wg4.w};
      float w1v[4]= {w14.x,w14.y,w14.z,w14.w};
#pragma unroll
      for (int k=0;k<4;++k)
#pragma unroll
        for (int j=0;j<8;++j){
          az[k][j] = fmaf(wzv[k], xv[j], az[k][j]);
          ag[k][j] = fmaf(wgv[k], xv[j], ag[k][j]);
          ah[k][j] = fmaf(w1v[k], xv[j], ah[k][j]);
        }
    }
  }

  // prefetch first W2 chunk
  vz0 = *(const float4*)(pw + OW2 + wo0*FH + wk*4);
  vz1 = *(const float4*)(pw + OW2 + wo1*FH + wk*4);

  __syncthreads();   // all waves done with Xs/W1s before Hs overwrites them

  // ---- phase B: h = relu(ah + b1) -> Hs ----
#pragma unroll
  for (int k=0;k<4;++k){
    float b1 = pw[OB1 + ty*4 + k];
#pragma unroll
    for (int h=0; h<2; ++h){
      float4 r;
      r.x = fmaxf(ah[k][h*4+0]+b1, 0.f);
      r.y = fmaxf(ah[k][h*4+1]+b1, 0.f);
      r.z = fmaxf(ah[k][h*4+2]+b1, 0.f);
      r.w = fmaxf(ah[k][h*4+3]+b1, 0.f);
      *(float4*)(&HS(ty*4+k, (tx+h*16)*4)) = r;
    }
  }

  // ---- phase C: K = 192..255 (h from LDS), 4 chunks ----
  for (int ci=0; ci<4; ++ci){
    __syncthreads();   // ci=0: Hs visible + Wzs free; ci>0: prev compute done
    WZS(wk*4+0,wo0)=vz0.x; WZS(wk*4+1,wo0)=vz0.y; WZS(wk*4+2,wo0)=vz0.z; WZS(wk*4+3,wo0)=vz0.w;
    WZS(wk*4+0,wo1)=vz1.x; WZS(wk*4+1,wo1)=vz1.y; WZS(wk*4+2,wo1)=vz1.z; WZS(wk*4+3,wo1)=vz1.w;
    if (ci+1 < 4){
      int cn = ci+1;
      vz0 = *(const float4*)(pw + OW2 + wo0*FH + cn*KC + wk*4);
      vz1 = *(const float4*)(pw + OW2 + wo1*FH + cn*KC + wk*4);
    }
    __syncthreads();
#pragma unroll 4
    for (int kk=0; kk<KC; ++kk){
      float4 xa = *(const float4*)(&HS(ci*KC+kk, tx*4));
      float4 xb = *(const float4*)(&HS(ci*KC+kk, (tx+16)*4));
      float4 wz4 = *(const float4*)(&WZS(kk, ty*4));
      float4 wg4 = *(const float4*)(&WZS(kk, 64+ty*4));
      float xv[8] = {xa.x,xa.y,xa.z,xa.w,xb.x,xb.y,xb.z,xb.w};
      float wzv[4]= {wz4.x,wz4.y,wz4.z,wz4.w};
      float wgv[4]= {wg4.x,wg4.y,wg4.z,wg4.w};
#pragma unroll
      for (int k=0;k<4;++k)
#pragma unroll
        for (int j=0;j<8;++j){
          az[k][j] = fmaf(wzv[k], xv[j], az[k][j]);
          ag[k][j] = fmaf(wgv[k], xv[j], ag[k][j]);
        }
    }
  }

  // ---- epilogue: out += lf * z * sigmoid(g) ----
  float lf = fminf(fmaxf(lfp[0], 0.001f), 1000.f);
#pragma unroll
  for (int k=0;k<4;++k){
    int o = ty*4 + k;
    float bz = pw[OB2 + o]      + pw[OBS + o];
    float bg = pw[OB2 + o + 64] + pw[OBS + o + 64];
    float* op = out + ((size_t)(b*64+o))*(size_t)HW + px0;
#pragma unroll
    for (int h=0; h<2; ++h){
      float4 ov = *(const float4*)(op + (tx + h*16)*4);
      float r[4];
#pragma unroll
      for (int j=0;j<4;++j){
        float z = az[k][h*4+j] + bz;
        float g = ag[k][h*4+j] + bg;
        r[j] = lf * z / (1.f + expf(-g));
      }
      ov.x += r[0]; ov.y += r[1]; ov.z += r[2]; ov.w += r[3];
      *(float4*)(op + (tx + h*16)*4) = ov;
    }
  }
}

// dst(2H x 2H) = gauss_blur( bilinear_up2(src) ), zero-padded blur, clamped bilinear
__global__ void k_upsample(const float* __restrict__ src, float* __restrict__ dst, int H, int lgH){
  int Hn = 2*H;
  int HWn = Hn*Hn;
  int bc = blockIdx.y;
  int opx = blockIdx.x*256 + threadIdx.x;
  const float* s = src + (size_t)bc*(size_t)(H*H);
  int oy = opx >> (lgH+1), ox = opx & (Hn-1);
  float acc = 0.f;
#pragma unroll
  for (int ky=0;ky<3;++ky){
    int yy = oy+ky-1; if (yy < 0 || yy >= Hn) continue;
    int iy = yy >> 1, ry = yy & 1;
    int y0 = ry ? iy : iy-1;
    int y1 = ry ? iy+1 : iy;
    float wy0 = ry ? 0.75f : 0.25f;
    float wy1 = 1.f - wy0;
    y0 = y0 < 0 ? 0 : y0;
    y1 = y1 > H-1 ? H-1 : y1;
#pragma unroll
    for (int kx=0;kx<3;++kx){
      int xx = ox+kx-1; if (xx < 0 || xx >= Hn) continue;
      int ix = xx >> 1, rx = xx & 1;
      int x0 = rx ? ix : ix-1;
      int x1 = rx ? ix+1 : ix;
      float wx0 = rx ? 0.75f : 0.25f;
      float wx1 = 1.f - wx0;
      x0 = x0 < 0 ? 0 : x0;
      x1 = x1 > H-1 ? H-1 : x1;
      float u = wy0*(wx0*s[y0*H+x0] + wx1*s[y0*H+x1])
              + wy1*(wx0*s[y1*H+x0] + wx1*s[y1*H+x1]);
      acc = fmaf(gk_at(ky,kx), u, acc);
    }
  }
  dst[(size_t)bc*(size_t)HWn + opx] = acc;
}

// Fused epilogue: h'=relu(r1w@t+r1b); t2 = t + r2w@h'+r2b; y = ocw@t2+ocb; write clip(y),raw(y)
__global__ void __launch_bounds__(256) k_final(const float* __restrict__ t,
    const float* __restrict__ r1w, const float* __restrict__ r1b,
    const float* __restrict__ r2w, const float* __restrict__ r2b,
    const float* __restrict__ ocw, const float* __restrict__ ocb,
    float* __restrict__ dout, int HW){
  __shared__ float Ts[64][132];
  __shared__ float Hs[64][132];
  __shared__ float Wb[64][68];
  int b = blockIdx.y;
  int tx = threadIdx.x, ty = threadIdx.y;
  int tid = ty*16 + tx;
  int px0 = blockIdx.x*TPX;

#pragma unroll
  for (int it=0; it<8; ++it){
    int idx = it*256 + tid;
    int ch = idx>>5, c4 = idx&31;
    *(float4*)(&Ts[ch][c4*4]) = *(const float4*)(t + ((size_t)(b*64+ch))*(size_t)HW + px0 + c4*4);
  }
#pragma unroll
  for (int it=0; it<4; ++it){
    int idx = it*256 + tid;
    int o = idx>>4, k4 = idx&15;
    float4 w = *(const float4*)(r1w + o*64 + k4*4);
    Wb[k4*4+0][o]=w.x; Wb[k4*4+1][o]=w.y; Wb[k4*4+2][o]=w.z; Wb[k4*4+3][o]=w.w;
  }
  __syncthreads();

  float acc[4][8];
#pragma unroll
  for (int k=0;k<4;++k)
#pragma unroll
    for (int j=0;j<8;++j) acc[k][j]=0.f;
#pragma unroll 4
  for (int kk=0; kk<64; ++kk){
    float4 xa = *(const float4*)(&Ts[kk][tx*4]);
    float4 xb = *(const float4*)(&Ts[kk][(tx+16)*4]);
    float4 w4 = *(const float4*)(&Wb[kk][ty*4]);
    float xv[8]={xa.x,xa.y,xa.z,xa.w,xb.x,xb.y,xb.z,xb.w};
    float wv[4]={w4.x,w4.y,w4.z,w4.w};
#pragma unroll
    for (int k=0;k<4;++k)
#pragma unroll
      for (int j=0;j<8;++j) acc[k][j] = fmaf(wv[k], xv[j], acc[k][j]);
  }
  __syncthreads();

#pragma unroll
  for (int k=0;k<4;++k){
    float bs = r1b[ty*4+k];
#pragma unroll
    for (int h=0; h<2; ++h){
      float4 r;
      r.x = fmaxf(acc[k][h*4+0]+bs, 0.f);
      r.y = fmaxf(acc[k][h*4+1]+bs, 0.f);
      r.z = fmaxf(acc[k][h*4+2]+bs, 0.f);
      r.w = fmaxf(acc[k][h*4+3]+bs, 0.f);
      *(float4*)(&Hs[ty*4+k][(tx+h*16)*4]) = r;
    }
  }
#pragma unroll
  for (int it=0; it<4; ++it){
    int idx = it*256 + tid;
    int o = idx>>4, k4 = idx&15;
    float4 w = *(const float4*)(r2w + o*64 + k4*4);
    Wb[k4*4+0][o]=w.x; Wb[k4*4+1][o]=w.y; Wb[k4*4+2][o]=w.z; Wb[k4*4+3][o]=w.w;
  }
  __syncthreads();

#pragma unroll
  for (int k=0;k<4;++k)
#pragma unroll
    for (int j=0;j<8;++j) acc[k][j]=0.f;
#pragma unroll 4
  for (int kk=0; kk<64; ++kk){
    float4 xa = *(const float4*)(&Hs[kk][tx*4]);
    float4 xb = *(const float4*)(&Hs[kk][(tx+16)*4]);
    float4 w4 = *(const float4*)(&Wb[kk][ty*4]);
    float xv[8]={xa.x,xa.y,xa.z,xa.w,xb.x,xb.y,xb.z,xb.w};
    float wv[4]={w4.x,w4.y,w4.z,w4.w};
#pragma unroll
    for (int k=0;k<4;++k)
#pragma unroll
      for (int j=0;j<8;++j) acc[k][j] = fmaf(wv[k], xv[j], acc[k][j]);
  }
#pragma unroll
  for (int k=0;k<4;++k){
    int o = ty*4 + k;
    float bs = r2b[o];
#pragma unroll
    for (int h=0; h<2; ++h){
      float4 tv = *(const float4*)(&Ts[o][(tx+h*16)*4]);
      tv.x += acc[k][h*4+0]+bs; tv.y += acc[k][h*4+1]+bs;
      tv.z += acc[k][h*4+2]+bs; tv.w += acc[k][h*4+3]+bs;
      *(float4*)(&Ts[o][(tx+h*16)*4]) = tv;
    }
  }
  __syncthreads();
  if (tid < 192){
    int c = tid>>6, kk = tid&63;
    Wb[kk][c] = ocw[c*64+kk];
  }
  __syncthreads();

  if (tid < 128){
    float a0=0.f, a1=0.f, a2=0.f;
#pragma unroll 4
    for (int kk=0; kk<64; ++kk){
      float x = Ts[kk][tid];
      a0 = fmaf(x, Wb[kk][0], a0);
      a1 = fmaf(x, Wb[kk][1], a1);
      a2 = fmaf(x, Wb[kk][2], a2);
    }
    size_t rawoff = (size_t)B*3*(size_t)HW;
    float y[3] = {a0+ocb[0], a1+ocb[1], a2+ocb[2]};
    int px = px0 + tid;
#pragma unroll
    for (int c=0;c<3;++c){
      size_t base = ((size_t)(b*3+c))*(size_t)HW + px;
      dout[base] = fminf(fmaxf(y[c],-1.f),1.f);
      dout[rawoff + base] = y[c];
    }
  }
}

extern "C" void kernel_launch(void* const* d_in, const int* in_sizes, int n_in,
                              void* d_out, int out_size, void* d_ws, size_t ws_size,
                              hipStream_t stream) {
  const float* lat = (const float*)d_in[0];
  const float* ca  = (const float*)d_in[1];
  const float* lfp = (const float*)d_in[3];
  const float* hw  = (const float*)d_in[4];
  const float* hb  = (const float*)d_in[5];
  const float* r1w = (const float*)d_in[6];
  const float* r1b = (const float*)d_in[7];
  const float* r2w = (const float*)d_in[8];
  const float* r2b = (const float*)d_in[9];
  const float* ocw = (const float*)d_in[10];
  const float* ocb = (const float*)d_in[11];
  float* dout = (float*)d_out;

  float* ws   = (float*)d_ws;
  float* p    = ws;                                     // B*PT
  float* outA = p    + (size_t)B*PT;                    // B*64*16384
  float* outB = outA + (size_t)B*64*16384;              // B*64*16384
  float* sob  = outB + (size_t)B*64*16384;              // B*128*16384
  float* stats= sob  + (size_t)B*128*16384;             // B*192*2

  k_hyper<<<dim3((PT+255)/256), dim3(256), 0, stream>>>(lat, hw, hb, p);
  k_init<<<dim3(B*64), dim3(256), 0, stream>>>(ca, outA);

  float* cur = outA;
  float* oth = outB;
  int H = 16, lgH = 4;
  for (int c = 0; c < 16; ++c){
    int HW = H*H;
    k_sobstat<<<dim3(B*64), dim3(256), 0, stream>>>(cur, sob, stats, H, lgH, HW);
    k_dyna<<<dim3(HW/TPX, B), dim3(16,16), 0, stream>>>(cur, sob, stats, p, lfp, HW);
    if (c < 15 && (c & 3) == 3){
      k_upsample<<<dim3((HW*4)/256, B*64), dim3(256), 0, stream>>>(cur, oth, H, lgH);
      float* tmp = cur; cur = oth; oth = tmp;
      H *= 2; lgH += 1;
    }
  }
  int HW = H*H;  // 16384
  k_final<<<dim3(HW/TPX, B), dim3(16,16), 0, stream>>>(cur, r1w, r1b, r2w, r2b, ocw, ocb, dout, HW);
}